// Round 10
// baseline (168.814 us; speedup 1.0000x reference)
//
#include <hip/hip_runtime.h>
#include <hip/hip_bf16.h>

typedef unsigned short ushort_t;
typedef __attribute__((ext_vector_type(8))) short short8;
typedef __attribute__((ext_vector_type(4))) float f32x4;

constexpr int B  = 2;
constexpr int T  = 2048;
constexpr int E  = 768;
constexpr int H  = 12;
constexpr int HD = 64;
// q pre-scale includes log2(e) so attention can use exp2 (bare v_exp_f32)
constexpr float QSCALE = 0.125f * 1.44269504088896f;

__device__ __forceinline__ ushort_t f2bf(float x) {
  unsigned int u = __float_as_uint(x);
  u += 0x7fffu + ((u >> 16) & 1u);
  return (ushort_t)(u >> 16);
}

__device__ __forceinline__ unsigned int pack_bf2(float a, float b) {
  __hip_bfloat162 h = __float22bfloat162_rn(float2{a, b});
  return *(unsigned int*)&h;
}

// XOR-swizzled LDS index, 64-ushort rows: 16B chunks, chunk ^= row&7.
__device__ __forceinline__ int swz(int row, int col) {
  return row * 64 + ((((col >> 3) ^ (row & 7)) << 3) | (col & 7));
}

// async global->LDS, 16B per lane; LDS dest = wave-uniform base + lane*16.
__device__ __forceinline__ void gl_lds16(const ushort_t* g, ushort_t* l) {
  __builtin_amdgcn_global_load_lds(
      (const __attribute__((address_space(1))) unsigned int*)g,
      (__attribute__((address_space(3))) unsigned int*)l, 16, 0, 0);
}

// ---------------------------------------------------------------------------
// Fused: fp32->bf16 convert for X + 4 weights, AND fp32 cos/sin rope tables.
// ---------------------------------------------------------------------------
__global__ __launch_bounds__(256) void cvt_all(
    const float* __restrict__ X,  const float* __restrict__ Wq,
    const float* __restrict__ Wk, const float* __restrict__ Wv,
    const float* __restrict__ Wo, const float* __restrict__ rope,
    ushort_t* __restrict__ Xb,  ushort_t* __restrict__ Wqb,
    ushort_t* __restrict__ Wkb, ushort_t* __restrict__ Wvb,
    ushort_t* __restrict__ Wob, float* __restrict__ ct, float* __restrict__ st)
{
  constexpr int NX4 = (B * T * E) / 4;
  constexpr int NW4 = (E * E) / 4;
  constexpr int NC4 = NX4 + 4 * NW4;
  int i = blockIdx.x * 256 + threadIdx.x;
  if (i < NC4) {
    const float* s; ushort_t* d; int j;
    if (i < NX4) { s = X; d = Xb; j = i; }
    else {
      int t = i - NX4;
      int w = t / NW4; j = t - w * NW4;
      s = (w == 0) ? Wq : (w == 1) ? Wk : (w == 2) ? Wv : Wo;
      d = (w == 0) ? Wqb : (w == 1) ? Wkb : (w == 2) ? Wvb : Wob;
    }
    float4 v = ((const float4*)s)[j];
    ushort4 o;
    o.x = f2bf(v.x); o.y = f2bf(v.y); o.z = f2bf(v.z); o.w = f2bf(v.w);
    ((ushort4*)d)[j] = o;
  } else {
    int j = (i - NC4) * 4;
    float4 f = *(const float4*)(rope + j);
    float c, s;
    sincosf(f.x, &s, &c); ct[j+0] = c; st[j+0] = s;
    sincosf(f.y, &s, &c); ct[j+1] = c; st[j+1] = s;
    sincosf(f.z, &s, &c); ct[j+2] = c; st[j+2] = s;
    sincosf(f.w, &s, &c); ct[j+3] = c; st[j+3] = s;
  }
}

// ---------------------------------------------------------------------------
// QKV projection. Tile 128(M)x64(N=one head), K-step 64. Staging via
// global_load_lds width=16 with PRE-SWIZZLED global gather (lane fetches
// chunk c = lane&7 ^ row&7) so data lands in the XOR-swizzled LDS layout.
// Rotary via tables. Epilogue writes MFMA FRAGMENT-ORDER global layouts:
//   Qf: per bh, per 16-q group: [kh:2][lane:64][8]  (B-frag, n=q)
//   Kf: per bh, per 64-k tile:  [mt:4][kh:2][lane:64][8]  (A-frag, m=kc)
//   Vf: per bh, per 64-k tile:  [nt:4][kh:2][lane:64][8]  (B-frag, n=d)
// ---------------------------------------------------------------------------
__global__ __launch_bounds__(256) void qkv_gemm(
    const ushort_t* __restrict__ Xb,
    const ushort_t* __restrict__ Wqb, const ushort_t* __restrict__ Wkb,
    const ushort_t* __restrict__ Wvb,
    const float* __restrict__ ct, const float* __restrict__ st,
    ushort_t* __restrict__ qfb, ushort_t* __restrict__ kfb, ushort_t* __restrict__ vfb)
{
  __shared__ __align__(16) ushort_t smem[128 * 64 + 64 * 64];
  ushort_t* Xs = smem;
  ushort_t* Ws = smem + 128 * 64;
  const int tid  = threadIdx.x;
  const int wave = tid >> 6;
  const int lane = tid & 63;
  const int l15  = lane & 15, quad = lane >> 4;
  const int n0 = blockIdx.x * 64;
  const int m0 = blockIdx.y * 128;
  const int z  = blockIdx.z;
  const ushort_t* Wt = (z == 0) ? Wqb : (z == 1) ? Wkb : Wvb;
  const int h = n0 >> 6;

  f32x4 acc[2][4];
  #pragma unroll
  for (int i = 0; i < 2; ++i)
    #pragma unroll
    for (int j = 0; j < 4; ++j) acc[i][j] = (f32x4){0.f, 0.f, 0.f, 0.f};

  // pre-swizzled gather addresses for global_load_lds staging
  const int li8 = lane >> 3, lc8 = lane & 7;
  const ushort_t* gX[4]; ushort_t* lX[4];
  #pragma unroll
  for (int j = 0; j < 4; ++j) {
    int row = wave * 32 + j * 8 + li8;
    int c = lc8 ^ (row & 7);
    gX[j] = Xb + (size_t)(m0 + row) * E + c * 8;
    lX[j] = Xs + (wave * 32 + j * 8) * 64;     // wave-uniform
  }
  const ushort_t* gW[2]; ushort_t* lW[2];
  #pragma unroll
  for (int j = 0; j < 2; ++j) {
    int row = wave * 16 + j * 8 + li8;
    int c = lc8 ^ (row & 7);
    gW[j] = Wt + (size_t)(n0 + row) * E + c * 8;
    lW[j] = Ws + (wave * 16 + j * 8) * 64;
  }

  for (int k0 = 0; k0 < E; k0 += 64) {
    #pragma unroll
    for (int j = 0; j < 4; ++j) gl_lds16(gX[j] + k0, lX[j]);
    #pragma unroll
    for (int j = 0; j < 2; ++j) gl_lds16(gW[j] + k0, lW[j]);
    __syncthreads();
    short8 a[2][2];
    #pragma unroll
    for (int mt = 0; mt < 2; ++mt)
      #pragma unroll
      for (int kh = 0; kh < 2; ++kh)
        a[mt][kh] = *(const short8*)&Xs[swz(wave * 32 + mt * 16 + l15, kh * 32 + quad * 8)];
    #pragma unroll
    for (int nt = 0; nt < 4; ++nt) {
      #pragma unroll
      for (int kh = 0; kh < 2; ++kh) {
        short8 bb = *(const short8*)&Ws[swz(nt * 16 + l15, kh * 32 + quad * 8)];
        #pragma unroll
        for (int mt = 0; mt < 2; ++mt)
          acc[mt][nt] = __builtin_amdgcn_mfma_f32_16x16x32_bf16(a[mt][kh], bb, acc[mt][nt], 0, 0, 0);
      }
    }
    __syncthreads();
  }

  const int b  = m0 >> 11;
  const int t0 = m0 & (T - 1);
  const int bh = b * H + h;
  const float qscale = (z == 0) ? QSCALE : 1.0f;

  if (z < 2) {
    #pragma unroll
    for (int mt = 0; mt < 2; ++mt) {
      #pragma unroll
      for (int r = 0; r < 4; ++r) {
        int mloc = wave * 32 + mt * 16 + quad * 4 + r;
        int t = (m0 + mloc) & (T - 1);
        float s0 = acc[mt][0][r] * qscale;
        float s1 = acc[mt][1][r] * qscale;
        float c0v = ct[t * 32 + l15],      sn0 = st[t * 32 + l15];
        float c1v = ct[t * 32 + 16 + l15], sn1 = st[t * 32 + 16 + l15];
        smem[swz(mloc, l15)]      = f2bf(s0 * c0v - s1 * sn0);
        smem[swz(mloc, 16 + l15)] = f2bf(s1 * c1v + s0 * sn1);
        smem[swz(mloc, 32 + l15)] = f2bf(acc[mt][2][r] * qscale);
        smem[swz(mloc, 48 + l15)] = f2bf(acc[mt][3][r] * qscale);
      }
    }
    __syncthreads();
    if (z == 0) {
      // Qf pieces: p = [qtl:8][kh:2][lane:64]
      #pragma unroll
      for (int i = 0; i < 4; ++i) {
        int p = tid + 256 * i;
        int qtl = p >> 7, kh = (p >> 6) & 1, ln = p & 63;
        int tl = qtl * 16 + (ln & 15);
        int d  = kh * 32 + (ln >> 4) * 8;
        uint4 v = *(const uint4*)&smem[swz(tl, d)];
        size_t off = ((size_t)((bh * 128 + (t0 >> 4) + qtl) * 2 + kh)) * 512 + ln * 8;
        *(uint4*)(qfb + off) = v;
      }
    } else {
      // Kf pieces: p = [ktl:2][mt:4][kh:2][lane:64]
      #pragma unroll
      for (int i = 0; i < 4; ++i) {
        int p = tid + 256 * i;
        int ktl = p >> 9, mt = (p >> 7) & 3, kh = (p >> 6) & 1, ln = p & 63;
        int tl = ktl * 64 + mt * 16 + (ln & 15);
        int d  = kh * 32 + (ln >> 4) * 8;
        uint4 v = *(const uint4*)&smem[swz(tl, d)];
        size_t off = ((size_t)(((bh * 32 + (t0 >> 6) + ktl) * 4 + mt) * 2 + kh)) * 512 + ln * 8;
        *(uint4*)(kfb + off) = v;
      }
    }
  } else {
    #pragma unroll
    for (int mt = 0; mt < 2; ++mt) {
      #pragma unroll
      for (int r = 0; r < 4; ++r) {
        int mloc = wave * 32 + mt * 16 + quad * 4 + r;
        int t = (m0 + mloc) & (T - 1);
        float s0 = acc[mt][0][r], s1 = acc[mt][1][r];
        float c0v = ct[t * 32 + l15],      sn0 = st[t * 32 + l15];
        float c1v = ct[t * 32 + 16 + l15], sn1 = st[t * 32 + 16 + l15];
        smem[(l15)      * 132 + mloc] = f2bf(s0 * c0v - s1 * sn0);
        smem[(16 + l15) * 132 + mloc] = f2bf(s1 * c1v + s0 * sn1);
        smem[(32 + l15) * 132 + mloc] = f2bf(acc[mt][2][r]);
        smem[(48 + l15) * 132 + mloc] = f2bf(acc[mt][3][r]);
      }
    }
    __syncthreads();
    // Vf pieces: p = [ktl:2][nt:4][kh:2][lane:64]
    #pragma unroll
    for (int i = 0; i < 4; ++i) {
      int p = tid + 256 * i;
      int ktl = p >> 9, nt = (p >> 7) & 3, kh = (p >> 6) & 1, ln = p & 63;
      int d  = nt * 16 + (ln & 15);
      int tl = ktl * 64 + kh * 32 + (ln >> 4) * 8;
      uint4 v = *(const uint4*)&smem[d * 132 + tl];
      size_t off = ((size_t)(((bh * 32 + (t0 >> 6) + ktl) * 4 + nt) * 2 + kh)) * 512 + ln * 8;
      *(uint4*)(vfb + off) = v;
    }
  }
}

// ---------------------------------------------------------------------------
// Flash attention, 2x2 wave split (R9-proven) + exp2 softmax (log2e folded
// into q upstream). Block = 64 q x bh; wave (wq,wk) computes its S quadrant;
// K/V frags direct from fragment-order global; no in-loop barriers.
// ---------------------------------------------------------------------------
__global__ __launch_bounds__(256) void attn_kernel(
    const ushort_t* __restrict__ qfb, const ushort_t* __restrict__ kfb,
    const ushort_t* __restrict__ vfb, ushort_t* __restrict__ cbuf)
{
  __shared__ __align__(16) ushort_t Ps[4][32 * 40];
  __shared__ __align__(16) float Osh[2][32][66];
  __shared__ float Lsh[2][32];
  const int tid  = threadIdx.x;
  const int wave = tid >> 6;
  const int wq = wave >> 1, wk = wave & 1;
  const int lane = tid & 63;
  const int l15  = lane & 15, quad = lane >> 4;
  const int q0 = blockIdx.x * 64;
  const int bh = blockIdx.y;
  const ushort_t* Qf = qfb + (size_t)bh * (T * HD);
  const ushort_t* Kf = kfb + (size_t)bh * (T * HD);
  const ushort_t* Vf = vfb + (size_t)bh * (T * HD);
  ushort_t* Pw = &Ps[wave][0];

  short8 qa[2][2];
  #pragma unroll
  for (int qg = 0; qg < 2; ++qg)
    #pragma unroll
    for (int kh = 0; kh < 2; ++kh)
      qa[qg][kh] = *(const short8*)(Qf + ((size_t)(((q0 >> 4) + wq * 2 + qg) * 2 + kh)) * 512 + lane * 8);

  short8 ka[2][2], va[4];
  #pragma unroll
  for (int i = 0; i < 2; ++i)
    #pragma unroll
    for (int kh = 0; kh < 2; ++kh)
      ka[i][kh] = *(const short8*)(Kf + ((size_t)((wk * 2 + i) * 2 + kh)) * 512 + lane * 8);
  #pragma unroll
  for (int nt = 0; nt < 4; ++nt)
    va[nt] = *(const short8*)(Vf + ((size_t)(nt * 2 + wk)) * 512 + lane * 8);

  f32x4 o[2][4];
  #pragma unroll
  for (int qg = 0; qg < 2; ++qg)
    #pragma unroll
    for (int nt = 0; nt < 4; ++nt) o[qg][nt] = (f32x4){0.f, 0.f, 0.f, 0.f};
  float lsum[2] = {0.f, 0.f};

  for (int kt = 0; kt < T / 64; ++kt) {
    const int ktn = (kt + 1 < T / 64) ? kt + 1 : kt;
    short8 kn[2][2], vn[4];
    #pragma unroll
    for (int i = 0; i < 2; ++i)
      #pragma unroll
      for (int kh = 0; kh < 2; ++kh)
        kn[i][kh] = *(const short8*)(Kf + ((size_t)((ktn * 4 + wk * 2 + i) * 2 + kh)) * 512 + lane * 8);
    #pragma unroll
    for (int nt = 0; nt < 4; ++nt)
      vn[nt] = *(const short8*)(Vf + ((size_t)((ktn * 4 + nt) * 2 + wk)) * 512 + lane * 8);

    f32x4 ss[2][2];
    #pragma unroll
    for (int mt = 0; mt < 2; ++mt)
      #pragma unroll
      for (int qg = 0; qg < 2; ++qg) {
        ss[mt][qg] = (f32x4){0.f, 0.f, 0.f, 0.f};
        ss[mt][qg] = __builtin_amdgcn_mfma_f32_16x16x32_bf16(ka[mt][0], qa[qg][0], ss[mt][qg], 0, 0, 0);
        ss[mt][qg] = __builtin_amdgcn_mfma_f32_16x16x32_bf16(ka[mt][1], qa[qg][1], ss[mt][qg], 0, 0, 0);
      }

    #pragma unroll
    for (int qg = 0; qg < 2; ++qg) {
      #pragma unroll
      for (int mt = 0; mt < 2; ++mt) {
        float p0 = exp2f(ss[mt][qg][0]);
        float p1 = exp2f(ss[mt][qg][1]);
        float p2 = exp2f(ss[mt][qg][2]);
        float p3 = exp2f(ss[mt][qg][3]);
        lsum[qg] += (p0 + p1) + (p2 + p3);
        uint2 w2;
        w2.x = pack_bf2(p0, p1);
        w2.y = pack_bf2(p2, p3);
        *(uint2*)&Pw[(qg * 16 + l15) * 40 + mt * 16 + quad * 4] = w2;
      }
    }

    short8 pa0 = *(const short8*)&Pw[(l15) * 40 + quad * 8];
    short8 pa1 = *(const short8*)&Pw[(16 + l15) * 40 + quad * 8];
    #pragma unroll
    for (int nt = 0; nt < 4; ++nt) {
      o[0][nt] = __builtin_amdgcn_mfma_f32_16x16x32_bf16(pa0, va[nt], o[0][nt], 0, 0, 0);
      o[1][nt] = __builtin_amdgcn_mfma_f32_16x16x32_bf16(pa1, va[nt], o[1][nt], 0, 0, 0);
    }

    #pragma unroll
    for (int i = 0; i < 2; ++i) {
      ka[i][0] = kn[i][0];
      ka[i][1] = kn[i][1];
    }
    #pragma unroll
    for (int nt = 0; nt < 4; ++nt) va[nt] = vn[nt];
  }

  #pragma unroll
  for (int qg = 0; qg < 2; ++qg) {
    lsum[qg] += __shfl_xor(lsum[qg], 16);
    lsum[qg] += __shfl_xor(lsum[qg], 32);
  }

  if (wk == 0) {
    #pragma unroll
    for (int qg = 0; qg < 2; ++qg)
      #pragma unroll
      for (int nt = 0; nt < 4; ++nt)
        #pragma unroll
        for (int r = 0; r < 4; ++r)
          Osh[wq][qg * 16 + quad * 4 + r][nt * 16 + l15] = o[qg][nt][r];
    if (lane < 16) {
      Lsh[wq][l15]      = lsum[0];
      Lsh[wq][16 + l15] = lsum[1];
    }
  }
  __syncthreads();
  if (wk == 1) {
    const int b = bh / H, h = bh % H;
    #pragma unroll
    for (int qg = 0; qg < 2; ++qg) {
      float ltot = lsum[qg] + Lsh[wq][qg * 16 + l15];
      float inv0 = 1.0f / ltot;
      #pragma unroll
      for (int r = 0; r < 4; ++r) {
        float inv = __shfl(inv0, quad * 4 + r);
        int t = q0 + wq * 32 + qg * 16 + quad * 4 + r;
        size_t base = ((size_t)b * T + t) * E + h * HD;
        #pragma unroll
        for (int nt = 0; nt < 4; ++nt) {
          float v = o[qg][nt][r] + Osh[wq][qg * 16 + quad * 4 + r][nt * 16 + l15];
          cbuf[base + nt * 16 + l15] = f2bf(v * inv);
        }
      }
    }
  }
}

// ---------------------------------------------------------------------------
// Output projection, 128x64 tile, K-step 64, global_load_lds staging
// (pre-swizzled gather), fp32 out + bias.
// ---------------------------------------------------------------------------
__global__ __launch_bounds__(256) void out_gemm(
    const ushort_t* __restrict__ Xc, const ushort_t* __restrict__ Wob,
    const float* __restrict__ bo, float* __restrict__ out)
{
  __shared__ __align__(16) ushort_t Xs[128 * 64];
  __shared__ __align__(16) ushort_t Ws[64 * 64];
  const int tid  = threadIdx.x;
  const int wave = tid >> 6;
  const int lane = tid & 63;
  const int l15  = lane & 15, quad = lane >> 4;
  const int n0 = blockIdx.x * 64;
  const int m0 = blockIdx.y * 128;

  f32x4 acc[2][4];
  #pragma unroll
  for (int i = 0; i < 2; ++i)
    #pragma unroll
    for (int j = 0; j < 4; ++j) acc[i][j] = (f32x4){0.f, 0.f, 0.f, 0.f};

  const int li8 = lane >> 3, lc8 = lane & 7;
  const ushort_t* gX[4]; ushort_t* lX[4];
  #pragma unroll
  for (int j = 0; j < 4; ++j) {
    int row = wave * 32 + j * 8 + li8;
    int c = lc8 ^ (row & 7);
    gX[j] = Xc + (size_t)(m0 + row) * E + c * 8;
    lX[j] = Xs + (wave * 32 + j * 8) * 64;
  }
  const ushort_t* gW[2]; ushort_t* lW[2];
  #pragma unroll
  for (int j = 0; j < 2; ++j) {
    int row = wave * 16 + j * 8 + li8;
    int c = lc8 ^ (row & 7);
    gW[j] = Wob + (size_t)(n0 + row) * E + c * 8;
    lW[j] = Ws + (wave * 16 + j * 8) * 64;
  }

  for (int k0 = 0; k0 < E; k0 += 64) {
    #pragma unroll
    for (int j = 0; j < 4; ++j) gl_lds16(gX[j] + k0, lX[j]);
    #pragma unroll
    for (int j = 0; j < 2; ++j) gl_lds16(gW[j] + k0, lW[j]);
    __syncthreads();
    short8 a[2][2];
    #pragma unroll
    for (int mt = 0; mt < 2; ++mt)
      #pragma unroll
      for (int kh = 0; kh < 2; ++kh)
        a[mt][kh] = *(const short8*)&Xs[swz(wave * 32 + mt * 16 + l15, kh * 32 + quad * 8)];
    #pragma unroll
    for (int nt = 0; nt < 4; ++nt) {
      #pragma unroll
      for (int kh = 0; kh < 2; ++kh) {
        short8 bb = *(const short8*)&Ws[swz(nt * 16 + l15, kh * 32 + quad * 8)];
        #pragma unroll
        for (int mt = 0; mt < 2; ++mt)
          acc[mt][nt] = __builtin_amdgcn_mfma_f32_16x16x32_bf16(a[mt][kh], bb, acc[mt][nt], 0, 0, 0);
      }
    }
    __syncthreads();
  }

  float bias[4];
  #pragma unroll
  for (int nt = 0; nt < 4; ++nt) bias[nt] = bo[n0 + nt * 16 + l15];
  #pragma unroll
  for (int mt = 0; mt < 2; ++mt) {
    #pragma unroll
    for (int r = 0; r < 4; ++r) {
      int m = m0 + wave * 32 + mt * 16 + quad * 4 + r;
      float* op = out + (size_t)m * E + n0;
      op[l15]      = acc[mt][0][r] + bias[0];
      op[16 + l15] = acc[mt][1][r] + bias[1];
      op[32 + l15] = acc[mt][2][r] + bias[2];
      op[48 + l15] = acc[mt][3][r] + bias[3];
    }
  }
}

// ---------------------------------------------------------------------------
extern "C" void kernel_launch(void* const* d_in, const int* in_sizes, int n_in,
                              void* d_out, int out_size, void* d_ws, size_t ws_size,
                              hipStream_t stream) {
  (void)in_sizes; (void)n_in; (void)out_size; (void)ws_size;
  const float* X    = (const float*)d_in[0];
  const float* rope = (const float*)d_in[1];
  const float* Wq   = (const float*)d_in[2];
  const float* Wk   = (const float*)d_in[3];
  const float* Wv   = (const float*)d_in[4];
  const float* Wo   = (const float*)d_in[5];
  const float* bo   = (const float*)d_in[6];
  float* out = (float*)d_out;

  const size_t NX = (size_t)B * T * E;
  const size_t NW = (size_t)E * E;
  const size_t NR = (size_t)T * 32;
  ushort_t* Xb  = (ushort_t*)d_ws;
  ushort_t* Wqb = Xb  + NX;
  ushort_t* Wkb = Wqb + NW;
  ushort_t* Wvb = Wkb + NW;
  ushort_t* Wob = Wvb + NW;
  ushort_t* qfb = Wob + NW;
  ushort_t* kfb = qfb + NX;
  ushort_t* vfb = kfb + NX;
  ushort_t* cb  = vfb + NX;
  float* ct = (float*)(cb + NX);
  float* st = ct + NR;

  const int total4 = (int)((NX + 4 * NW + NR) / 4);
  cvt_all<<<total4 / 256, 256, 0, stream>>>(X, Wq, Wk, Wv, Wo, rope,
                                            Xb, Wqb, Wkb, Wvb, Wob, ct, st);

  qkv_gemm<<<dim3(E / 64, (B * T) / 128, 3), 256, 0, stream>>>(
      Xb, Wqb, Wkb, Wvb, ct, st, qfb, kfb, vfb);
  attn_kernel<<<dim3(T / 64, B * H), 256, 0, stream>>>(qfb, kfb, vfb, cb);
  out_gemm<<<dim3(E / 64, (B * T) / 128), 256, 0, stream>>>(cb, Wob, bo, out);
}

// Round 11
// 162.644 us; speedup vs baseline: 1.0379x; 1.0379x over previous
//
#include <hip/hip_runtime.h>
#include <hip/hip_bf16.h>

typedef unsigned short ushort_t;
typedef __attribute__((ext_vector_type(8))) short short8;
typedef __attribute__((ext_vector_type(4))) float f32x4;

constexpr int B  = 2;
constexpr int T  = 2048;
constexpr int E  = 768;
constexpr int H  = 12;
constexpr int HD = 64;
constexpr float QSCALE = 0.125f;

__device__ __forceinline__ ushort_t f2bf(float x) {
  unsigned int u = __float_as_uint(x);
  u += 0x7fffu + ((u >> 16) & 1u);
  return (ushort_t)(u >> 16);
}

__device__ __forceinline__ unsigned int pack_bf2(float a, float b) {
  __hip_bfloat162 h = __float22bfloat162_rn(float2{a, b});
  return *(unsigned int*)&h;
}

// XOR-swizzled LDS index, 64-ushort rows: 16B chunks, chunk ^= row&7.
__device__ __forceinline__ int swz(int row, int col) {
  return row * 64 + ((((col >> 3) ^ (row & 7)) << 3) | (col & 7));
}

// async global->LDS, 16B per lane; LDS dest = wave-uniform base + lane*16.
__device__ __forceinline__ void gl_lds16(const ushort_t* g, ushort_t* l) {
  __builtin_amdgcn_global_load_lds(
      (const __attribute__((address_space(1))) unsigned int*)g,
      (__attribute__((address_space(3))) unsigned int*)l, 16, 0, 0);
}

// ---------------------------------------------------------------------------
// Fused: fp32->bf16 convert for X + 4 weights, AND fp32 cos/sin rope tables.
// ---------------------------------------------------------------------------
__global__ __launch_bounds__(256) void cvt_all(
    const float* __restrict__ X,  const float* __restrict__ Wq,
    const float* __restrict__ Wk, const float* __restrict__ Wv,
    const float* __restrict__ Wo, const float* __restrict__ rope,
    ushort_t* __restrict__ Xb,  ushort_t* __restrict__ Wqb,
    ushort_t* __restrict__ Wkb, ushort_t* __restrict__ Wvb,
    ushort_t* __restrict__ Wob, float* __restrict__ ct, float* __restrict__ st)
{
  constexpr int NX4 = (B * T * E) / 4;
  constexpr int NW4 = (E * E) / 4;
  constexpr int NC4 = NX4 + 4 * NW4;
  int i = blockIdx.x * 256 + threadIdx.x;
  if (i < NC4) {
    const float* s; ushort_t* d; int j;
    if (i < NX4) { s = X; d = Xb; j = i; }
    else {
      int t = i - NX4;
      int w = t / NW4; j = t - w * NW4;
      s = (w == 0) ? Wq : (w == 1) ? Wk : (w == 2) ? Wv : Wo;
      d = (w == 0) ? Wqb : (w == 1) ? Wkb : (w == 2) ? Wvb : Wob;
    }
    float4 v = ((const float4*)s)[j];
    ushort4 o;
    o.x = f2bf(v.x); o.y = f2bf(v.y); o.z = f2bf(v.z); o.w = f2bf(v.w);
    ((ushort4*)d)[j] = o;
  } else {
    int j = (i - NC4) * 4;
    float4 f = *(const float4*)(rope + j);
    float c, s;
    sincosf(f.x, &s, &c); ct[j+0] = c; st[j+0] = s;
    sincosf(f.y, &s, &c); ct[j+1] = c; st[j+1] = s;
    sincosf(f.z, &s, &c); ct[j+2] = c; st[j+2] = s;
    sincosf(f.w, &s, &c); ct[j+3] = c; st[j+3] = s;
  }
}

// ---------------------------------------------------------------------------
// Z-FUSED QKV projection: block = 128 rows x ONE head, computes Q, K and V
// together. X staged once per K-iter for all three outputs; 48 MFMAs per
// wave per barrier pair. Staging via global_load_lds width=16 pre-swizzled.
// Epilogue (3 barrier-separated phases) writes MFMA FRAGMENT-ORDER layouts:
//   Qf: per bh, per 16-q group: [kh:2][lane:64][8]  (B-frag, n=q)
//   Kf: per bh, per 64-k tile:  [mt:4][kh:2][lane:64][8]  (A-frag, m=kc)
//   Vf: per bh, per 64-k tile:  [nt:4][kh:2][lane:64][8]  (B-frag, n=d)
// ---------------------------------------------------------------------------
__global__ __launch_bounds__(256) void qkv_gemm(
    const ushort_t* __restrict__ Xb,
    const ushort_t* __restrict__ Wqb, const ushort_t* __restrict__ Wkb,
    const ushort_t* __restrict__ Wvb,
    const float* __restrict__ ct, const float* __restrict__ st,
    ushort_t* __restrict__ qfb, ushort_t* __restrict__ kfb, ushort_t* __restrict__ vfb)
{
  // Xs 128x64 (8192) + Ws[3] 64x64 (3*4096) = 20480 ush = 40 KB.
  // Epilogue reuses base region (Q/K: 8192 swz; V: 64x132 = 8448).
  __shared__ __align__(16) ushort_t smem[128 * 64 + 3 * 64 * 64];
  ushort_t* Xs = smem;
  ushort_t* Ws[3] = { smem + 8192, smem + 8192 + 4096, smem + 8192 + 8192 };
  const int tid  = threadIdx.x;
  const int wave = tid >> 6;
  const int lane = tid & 63;
  const int l15  = lane & 15, quad = lane >> 4;
  const int h  = blockIdx.x;           // head
  const int n0 = h * 64;
  const int m0 = blockIdx.y * 128;
  const ushort_t* Wsrc[3] = { Wqb, Wkb, Wvb };

  f32x4 acc[3][2][4];
  #pragma unroll
  for (int z = 0; z < 3; ++z)
    #pragma unroll
    for (int i = 0; i < 2; ++i)
      #pragma unroll
      for (int j = 0; j < 4; ++j) acc[z][i][j] = (f32x4){0.f, 0.f, 0.f, 0.f};

  // pre-swizzled gather addresses for global_load_lds staging
  const int li8 = lane >> 3, lc8 = lane & 7;
  const ushort_t* gX[4]; ushort_t* lX[4];
  #pragma unroll
  for (int j = 0; j < 4; ++j) {
    int row = wave * 32 + j * 8 + li8;
    int c = lc8 ^ (row & 7);
    gX[j] = Xb + (size_t)(m0 + row) * E + c * 8;
    lX[j] = Xs + (wave * 32 + j * 8) * 64;
  }
  const ushort_t* gW[3][2]; ushort_t* lW[3][2];
  #pragma unroll
  for (int z = 0; z < 3; ++z)
    #pragma unroll
    for (int j = 0; j < 2; ++j) {
      int row = wave * 16 + j * 8 + li8;
      int c = lc8 ^ (row & 7);
      gW[z][j] = Wsrc[z] + (size_t)(n0 + row) * E + c * 8;
      lW[z][j] = Ws[z] + (wave * 16 + j * 8) * 64;
    }

  for (int k0 = 0; k0 < E; k0 += 64) {
    #pragma unroll
    for (int j = 0; j < 4; ++j) gl_lds16(gX[j] + k0, lX[j]);
    #pragma unroll
    for (int z = 0; z < 3; ++z)
      #pragma unroll
      for (int j = 0; j < 2; ++j) gl_lds16(gW[z][j] + k0, lW[z][j]);
    __syncthreads();
    short8 a[2][2];
    #pragma unroll
    for (int mt = 0; mt < 2; ++mt)
      #pragma unroll
      for (int kh = 0; kh < 2; ++kh)
        a[mt][kh] = *(const short8*)&Xs[swz(wave * 32 + mt * 16 + l15, kh * 32 + quad * 8)];
    #pragma unroll
    for (int z = 0; z < 3; ++z)
      #pragma unroll
      for (int nt = 0; nt < 4; ++nt)
        #pragma unroll
        for (int kh = 0; kh < 2; ++kh) {
          short8 bb = *(const short8*)&Ws[z][swz(nt * 16 + l15, kh * 32 + quad * 8)];
          #pragma unroll
          for (int mt = 0; mt < 2; ++mt)
            acc[z][mt][nt] = __builtin_amdgcn_mfma_f32_16x16x32_bf16(a[mt][kh], bb, acc[z][mt][nt], 0, 0, 0);
        }
    __syncthreads();
  }

  const int b  = m0 >> 11;
  const int t0 = m0 & (T - 1);
  const int bh = b * H + h;

  // ---- phase Q, then K: rotate -> swz LDS -> fragment-order piece stores ----
  #pragma unroll
  for (int z = 0; z < 2; ++z) {
    const float sc = (z == 0) ? QSCALE : 1.0f;
    #pragma unroll
    for (int mt = 0; mt < 2; ++mt) {
      #pragma unroll
      for (int r = 0; r < 4; ++r) {
        int mloc = wave * 32 + mt * 16 + quad * 4 + r;
        int t = (m0 + mloc) & (T - 1);
        float s0 = acc[z][mt][0][r] * sc;
        float s1 = acc[z][mt][1][r] * sc;
        float c0v = ct[t * 32 + l15],      sn0 = st[t * 32 + l15];
        float c1v = ct[t * 32 + 16 + l15], sn1 = st[t * 32 + 16 + l15];
        smem[swz(mloc, l15)]      = f2bf(s0 * c0v - s1 * sn0);
        smem[swz(mloc, 16 + l15)] = f2bf(s1 * c1v + s0 * sn1);
        smem[swz(mloc, 32 + l15)] = f2bf(acc[z][mt][2][r] * sc);
        smem[swz(mloc, 48 + l15)] = f2bf(acc[z][mt][3][r] * sc);
      }
    }
    __syncthreads();
    if (z == 0) {
      // Qf pieces: p = [qtl:8][kh:2][lane:64]
      #pragma unroll
      for (int i = 0; i < 4; ++i) {
        int p = tid + 256 * i;
        int qtl = p >> 7, kh = (p >> 6) & 1, ln = p & 63;
        int tl = qtl * 16 + (ln & 15);
        int d  = kh * 32 + (ln >> 4) * 8;
        uint4 v = *(const uint4*)&smem[swz(tl, d)];
        size_t off = ((size_t)((bh * 128 + (t0 >> 4) + qtl) * 2 + kh)) * 512 + ln * 8;
        *(uint4*)(qfb + off) = v;
      }
    } else {
      // Kf pieces: p = [ktl:2][mt:4][kh:2][lane:64]
      #pragma unroll
      for (int i = 0; i < 4; ++i) {
        int p = tid + 256 * i;
        int ktl = p >> 9, mt = (p >> 7) & 3, kh = (p >> 6) & 1, ln = p & 63;
        int tl = ktl * 64 + mt * 16 + (ln & 15);
        int d  = kh * 32 + (ln >> 4) * 8;
        uint4 v = *(const uint4*)&smem[swz(tl, d)];
        size_t off = ((size_t)(((bh * 32 + (t0 >> 6) + ktl) * 4 + mt) * 2 + kh)) * 512 + ln * 8;
        *(uint4*)(kfb + off) = v;
      }
    }
    __syncthreads();
  }

  // ---- phase V: rotate -> transposed LDS (d, t_local) stride 132 -> pieces ----
  #pragma unroll
  for (int mt = 0; mt < 2; ++mt) {
    #pragma unroll
    for (int r = 0; r < 4; ++r) {
      int mloc = wave * 32 + mt * 16 + quad * 4 + r;
      int t = (m0 + mloc) & (T - 1);
      float s0 = acc[2][mt][0][r], s1 = acc[2][mt][1][r];
      float c0v = ct[t * 32 + l15],      sn0 = st[t * 32 + l15];
      float c1v = ct[t * 32 + 16 + l15], sn1 = st[t * 32 + 16 + l15];
      smem[(l15)      * 132 + mloc] = f2bf(s0 * c0v - s1 * sn0);
      smem[(16 + l15) * 132 + mloc] = f2bf(s1 * c1v + s0 * sn1);
      smem[(32 + l15) * 132 + mloc] = f2bf(acc[2][mt][2][r]);
      smem[(48 + l15) * 132 + mloc] = f2bf(acc[2][mt][3][r]);
    }
  }
  __syncthreads();
  // Vf pieces: p = [ktl:2][nt:4][kh:2][lane:64]
  #pragma unroll
  for (int i = 0; i < 4; ++i) {
    int p = tid + 256 * i;
    int ktl = p >> 9, nt = (p >> 7) & 3, kh = (p >> 6) & 1, ln = p & 63;
    int d  = nt * 16 + (ln & 15);
    int tl = ktl * 64 + kh * 32 + (ln >> 4) * 8;
    uint4 v = *(const uint4*)&smem[d * 132 + tl];
    size_t off = ((size_t)(((bh * 32 + (t0 >> 6) + ktl) * 4 + nt) * 2 + kh)) * 512 + ln * 8;
    *(uint4*)(vfb + off) = v;
  }
}

// ---------------------------------------------------------------------------
// Flash attention, 2x2 wave split (R9-proven, __expf). Block = 64 q x bh;
// wave (wq,wk) computes its S quadrant; K/V frags direct from fragment-order
// global; no in-loop barriers; static max; per-lane denominator.
// ---------------------------------------------------------------------------
__global__ __launch_bounds__(256) void attn_kernel(
    const ushort_t* __restrict__ qfb, const ushort_t* __restrict__ kfb,
    const ushort_t* __restrict__ vfb, ushort_t* __restrict__ cbuf)
{
  __shared__ __align__(16) ushort_t Ps[4][32 * 40];
  __shared__ __align__(16) float Osh[2][32][66];
  __shared__ float Lsh[2][32];
  const int tid  = threadIdx.x;
  const int wave = tid >> 6;
  const int wq = wave >> 1, wk = wave & 1;
  const int lane = tid & 63;
  const int l15  = lane & 15, quad = lane >> 4;
  const int q0 = blockIdx.x * 64;
  const int bh = blockIdx.y;
  const ushort_t* Qf = qfb + (size_t)bh * (T * HD);
  const ushort_t* Kf = kfb + (size_t)bh * (T * HD);
  const ushort_t* Vf = vfb + (size_t)bh * (T * HD);
  ushort_t* Pw = &Ps[wave][0];

  short8 qa[2][2];
  #pragma unroll
  for (int qg = 0; qg < 2; ++qg)
    #pragma unroll
    for (int kh = 0; kh < 2; ++kh)
      qa[qg][kh] = *(const short8*)(Qf + ((size_t)(((q0 >> 4) + wq * 2 + qg) * 2 + kh)) * 512 + lane * 8);

  short8 ka[2][2], va[4];
  #pragma unroll
  for (int i = 0; i < 2; ++i)
    #pragma unroll
    for (int kh = 0; kh < 2; ++kh)
      ka[i][kh] = *(const short8*)(Kf + ((size_t)((wk * 2 + i) * 2 + kh)) * 512 + lane * 8);
  #pragma unroll
  for (int nt = 0; nt < 4; ++nt)
    va[nt] = *(const short8*)(Vf + ((size_t)(nt * 2 + wk)) * 512 + lane * 8);

  f32x4 o[2][4];
  #pragma unroll
  for (int qg = 0; qg < 2; ++qg)
    #pragma unroll
    for (int nt = 0; nt < 4; ++nt) o[qg][nt] = (f32x4){0.f, 0.f, 0.f, 0.f};
  float lsum[2] = {0.f, 0.f};

  for (int kt = 0; kt < T / 64; ++kt) {
    const int ktn = (kt + 1 < T / 64) ? kt + 1 : kt;
    short8 kn[2][2], vn[4];
    #pragma unroll
    for (int i = 0; i < 2; ++i)
      #pragma unroll
      for (int kh = 0; kh < 2; ++kh)
        kn[i][kh] = *(const short8*)(Kf + ((size_t)((ktn * 4 + wk * 2 + i) * 2 + kh)) * 512 + lane * 8);
    #pragma unroll
    for (int nt = 0; nt < 4; ++nt)
      vn[nt] = *(const short8*)(Vf + ((size_t)((ktn * 4 + nt) * 2 + wk)) * 512 + lane * 8);

    f32x4 ss[2][2];
    #pragma unroll
    for (int mt = 0; mt < 2; ++mt)
      #pragma unroll
      for (int qg = 0; qg < 2; ++qg) {
        ss[mt][qg] = (f32x4){0.f, 0.f, 0.f, 0.f};
        ss[mt][qg] = __builtin_amdgcn_mfma_f32_16x16x32_bf16(ka[mt][0], qa[qg][0], ss[mt][qg], 0, 0, 0);
        ss[mt][qg] = __builtin_amdgcn_mfma_f32_16x16x32_bf16(ka[mt][1], qa[qg][1], ss[mt][qg], 0, 0, 0);
      }

    #pragma unroll
    for (int qg = 0; qg < 2; ++qg) {
      #pragma unroll
      for (int mt = 0; mt < 2; ++mt) {
        float p0 = __expf(ss[mt][qg][0]);
        float p1 = __expf(ss[mt][qg][1]);
        float p2 = __expf(ss[mt][qg][2]);
        float p3 = __expf(ss[mt][qg][3]);
        lsum[qg] += (p0 + p1) + (p2 + p3);
        uint2 w2;
        w2.x = pack_bf2(p0, p1);
        w2.y = pack_bf2(p2, p3);
        *(uint2*)&Pw[(qg * 16 + l15) * 40 + mt * 16 + quad * 4] = w2;
      }
    }

    short8 pa0 = *(const short8*)&Pw[(l15) * 40 + quad * 8];
    short8 pa1 = *(const short8*)&Pw[(16 + l15) * 40 + quad * 8];
    #pragma unroll
    for (int nt = 0; nt < 4; ++nt) {
      o[0][nt] = __builtin_amdgcn_mfma_f32_16x16x32_bf16(pa0, va[nt], o[0][nt], 0, 0, 0);
      o[1][nt] = __builtin_amdgcn_mfma_f32_16x16x32_bf16(pa1, va[nt], o[1][nt], 0, 0, 0);
    }

    #pragma unroll
    for (int i = 0; i < 2; ++i) {
      ka[i][0] = kn[i][0];
      ka[i][1] = kn[i][1];
    }
    #pragma unroll
    for (int nt = 0; nt < 4; ++nt) va[nt] = vn[nt];
  }

  #pragma unroll
  for (int qg = 0; qg < 2; ++qg) {
    lsum[qg] += __shfl_xor(lsum[qg], 16);
    lsum[qg] += __shfl_xor(lsum[qg], 32);
  }

  if (wk == 0) {
    #pragma unroll
    for (int qg = 0; qg < 2; ++qg)
      #pragma unroll
      for (int nt = 0; nt < 4; ++nt)
        #pragma unroll
        for (int r = 0; r < 4; ++r)
          Osh[wq][qg * 16 + quad * 4 + r][nt * 16 + l15] = o[qg][nt][r];
    if (lane < 16) {
      Lsh[wq][l15]      = lsum[0];
      Lsh[wq][16 + l15] = lsum[1];
    }
  }
  __syncthreads();
  if (wk == 1) {
    const int b = bh / H, h = bh % H;
    #pragma unroll
    for (int qg = 0; qg < 2; ++qg) {
      float ltot = lsum[qg] + Lsh[wq][qg * 16 + l15];
      float inv0 = 1.0f / ltot;
      #pragma unroll
      for (int r = 0; r < 4; ++r) {
        float inv = __shfl(inv0, quad * 4 + r);
        int t = q0 + wq * 32 + qg * 16 + quad * 4 + r;
        size_t base = ((size_t)b * T + t) * E + h * HD;
        #pragma unroll
        for (int nt = 0; nt < 4; ++nt) {
          float v = o[qg][nt][r] + Osh[wq][qg * 16 + quad * 4 + r][nt * 16 + l15];
          cbuf[base + nt * 16 + l15] = f2bf(v * inv);
        }
      }
    }
  }
}

// ---------------------------------------------------------------------------
// Output projection, 128x64 tile, K-step 64, global_load_lds staging
// (pre-swizzled gather), fp32 out + bias.
// ---------------------------------------------------------------------------
__global__ __launch_bounds__(256) void out_gemm(
    const ushort_t* __restrict__ Xc, const ushort_t* __restrict__ Wob,
    const float* __restrict__ bo, float* __restrict__ out)
{
  __shared__ __align__(16) ushort_t Xs[128 * 64];
  __shared__ __align__(16) ushort_t Ws[64 * 64];
  const int tid  = threadIdx.x;
  const int wave = tid >> 6;
  const int lane = tid & 63;
  const int l15  = lane & 15, quad = lane >> 4;
  const int n0 = blockIdx.x * 64;
  const int m0 = blockIdx.y * 128;

  f32x4 acc[2][4];
  #pragma unroll
  for (int i = 0; i < 2; ++i)
    #pragma unroll
    for (int j = 0; j < 4; ++j) acc[i][j] = (f32x4){0.f, 0.f, 0.f, 0.f};

  const int li8 = lane >> 3, lc8 = lane & 7;
  const ushort_t* gX[4]; ushort_t* lX[4];
  #pragma unroll
  for (int j = 0; j < 4; ++j) {
    int row = wave * 32 + j * 8 + li8;
    int c = lc8 ^ (row & 7);
    gX[j] = Xc + (size_t)(m0 + row) * E + c * 8;
    lX[j] = Xs + (wave * 32 + j * 8) * 64;
  }
  const ushort_t* gW[2]; ushort_t* lW[2];
  #pragma unroll
  for (int j = 0; j < 2; ++j) {
    int row = wave * 16 + j * 8 + li8;
    int c = lc8 ^ (row & 7);
    gW[j] = Wob + (size_t)(n0 + row) * E + c * 8;
    lW[j] = Ws + (wave * 16 + j * 8) * 64;
  }

  for (int k0 = 0; k0 < E; k0 += 64) {
    #pragma unroll
    for (int j = 0; j < 4; ++j) gl_lds16(gX[j] + k0, lX[j]);
    #pragma unroll
    for (int j = 0; j < 2; ++j) gl_lds16(gW[j] + k0, lW[j]);
    __syncthreads();
    short8 a[2][2];
    #pragma unroll
    for (int mt = 0; mt < 2; ++mt)
      #pragma unroll
      for (int kh = 0; kh < 2; ++kh)
        a[mt][kh] = *(const short8*)&Xs[swz(wave * 32 + mt * 16 + l15, kh * 32 + quad * 8)];
    #pragma unroll
    for (int nt = 0; nt < 4; ++nt) {
      #pragma unroll
      for (int kh = 0; kh < 2; ++kh) {
        short8 bb = *(const short8*)&Ws[swz(nt * 16 + l15, kh * 32 + quad * 8)];
        #pragma unroll
        for (int mt = 0; mt < 2; ++mt)
          acc[mt][nt] = __builtin_amdgcn_mfma_f32_16x16x32_bf16(a[mt][kh], bb, acc[mt][nt], 0, 0, 0);
      }
    }
    __syncthreads();
  }

  float bias[4];
  #pragma unroll
  for (int nt = 0; nt < 4; ++nt) bias[nt] = bo[n0 + nt * 16 + l15];
  #pragma unroll
  for (int mt = 0; mt < 2; ++mt) {
    #pragma unroll
    for (int r = 0; r < 4; ++r) {
      int m = m0 + wave * 32 + mt * 16 + quad * 4 + r;
      float* op = out + (size_t)m * E + n0;
      op[l15]      = acc[mt][0][r] + bias[0];
      op[16 + l15] = acc[mt][1][r] + bias[1];
      op[32 + l15] = acc[mt][2][r] + bias[2];
      op[48 + l15] = acc[mt][3][r] + bias[3];
    }
  }
}

// ---------------------------------------------------------------------------
extern "C" void kernel_launch(void* const* d_in, const int* in_sizes, int n_in,
                              void* d_out, int out_size, void* d_ws, size_t ws_size,
                              hipStream_t stream) {
  (void)in_sizes; (void)n_in; (void)out_size; (void)ws_size;
  const float* X    = (const float*)d_in[0];
  const float* rope = (const float*)d_in[1];
  const float* Wq   = (const float*)d_in[2];
  const float* Wk   = (const float*)d_in[3];
  const float* Wv   = (const float*)d_in[4];
  const float* Wo   = (const float*)d_in[5];
  const float* bo   = (const float*)d_in[6];
  float* out = (float*)d_out;

  const size_t NX = (size_t)B * T * E;
  const size_t NW = (size_t)E * E;
  const size_t NR = (size_t)T * 32;
  ushort_t* Xb  = (ushort_t*)d_ws;
  ushort_t* Wqb = Xb  + NX;
  ushort_t* Wkb = Wqb + NW;
  ushort_t* Wvb = Wkb + NW;
  ushort_t* Wob = Wvb + NW;
  ushort_t* qfb = Wob + NW;
  ushort_t* kfb = qfb + NX;
  ushort_t* vfb = kfb + NX;
  ushort_t* cb  = vfb + NX;
  float* ct = (float*)(cb + NX);
  float* st = ct + NR;

  const int total4 = (int)((NX + 4 * NW + NR) / 4);
  cvt_all<<<total4 / 256, 256, 0, stream>>>(X, Wq, Wk, Wv, Wo, rope,
                                            Xb, Wqb, Wkb, Wvb, Wob, ct, st);

  qkv_gemm<<<dim3(H, (B * T) / 128), 256, 0, stream>>>(
      Xb, Wqb, Wkb, Wvb, ct, st, qfb, kfb, vfb);
  attn_kernel<<<dim3(T / 64, B * H), 256, 0, stream>>>(qfb, kfb, vfb, cb);
  out_gemm<<<dim3(E / 64, (B * T) / 128), 256, 0, stream>>>(cb, Wob, bo, out);
}

// Round 12
// 158.265 us; speedup vs baseline: 1.0667x; 1.0277x over previous
//
#include <hip/hip_runtime.h>
#include <hip/hip_bf16.h>

typedef unsigned short ushort_t;
typedef __attribute__((ext_vector_type(8))) short short8;
typedef __attribute__((ext_vector_type(4))) float f32x4;

constexpr int B  = 2;
constexpr int T  = 2048;
constexpr int E  = 768;
constexpr int H  = 12;
constexpr int HD = 64;
constexpr float QSCALE = 0.125f;

__device__ __forceinline__ ushort_t f2bf(float x) {
  unsigned int u = __float_as_uint(x);
  u += 0x7fffu + ((u >> 16) & 1u);
  return (ushort_t)(u >> 16);
}

__device__ __forceinline__ unsigned int pack_bf2(float a, float b) {
  __hip_bfloat162 h = __float22bfloat162_rn(float2{a, b});
  return *(unsigned int*)&h;
}

// XOR-swizzled LDS index, 64-ushort rows: 16B chunks, chunk ^= row&7.
__device__ __forceinline__ int swz(int row, int col) {
  return row * 64 + ((((col >> 3) ^ (row & 7)) << 3) | (col & 7));
}

// async global->LDS, 16B per lane; LDS dest = wave-uniform base + lane*16.
__device__ __forceinline__ void gl_lds16(const ushort_t* g, ushort_t* l) {
  __builtin_amdgcn_global_load_lds(
      (const __attribute__((address_space(1))) unsigned int*)g,
      (__attribute__((address_space(3))) unsigned int*)l, 16, 0, 0);
}

// ---------------------------------------------------------------------------
// Fused: fp32->bf16 convert for X + 4 weights, AND fp32 cos/sin rope tables.
// ---------------------------------------------------------------------------
__global__ __launch_bounds__(256) void cvt_all(
    const float* __restrict__ X,  const float* __restrict__ Wq,
    const float* __restrict__ Wk, const float* __restrict__ Wv,
    const float* __restrict__ Wo, const float* __restrict__ rope,
    ushort_t* __restrict__ Xb,  ushort_t* __restrict__ Wqb,
    ushort_t* __restrict__ Wkb, ushort_t* __restrict__ Wvb,
    ushort_t* __restrict__ Wob, float* __restrict__ ct, float* __restrict__ st)
{
  constexpr int NX4 = (B * T * E) / 4;
  constexpr int NW4 = (E * E) / 4;
  constexpr int NC4 = NX4 + 4 * NW4;
  int i = blockIdx.x * 256 + threadIdx.x;
  if (i < NC4) {
    const float* s; ushort_t* d; int j;
    if (i < NX4) { s = X; d = Xb; j = i; }
    else {
      int t = i - NX4;
      int w = t / NW4; j = t - w * NW4;
      s = (w == 0) ? Wq : (w == 1) ? Wk : (w == 2) ? Wv : Wo;
      d = (w == 0) ? Wqb : (w == 1) ? Wkb : (w == 2) ? Wvb : Wob;
    }
    float4 v = ((const float4*)s)[j];
    ushort4 o;
    o.x = f2bf(v.x); o.y = f2bf(v.y); o.z = f2bf(v.z); o.w = f2bf(v.w);
    ((ushort4*)d)[j] = o;
  } else {
    int j = (i - NC4) * 4;
    float4 f = *(const float4*)(rope + j);
    float c, s;
    sincosf(f.x, &s, &c); ct[j+0] = c; st[j+0] = s;
    sincosf(f.y, &s, &c); ct[j+1] = c; st[j+1] = s;
    sincosf(f.z, &s, &c); ct[j+2] = c; st[j+2] = s;
    sincosf(f.w, &s, &c); ct[j+3] = c; st[j+3] = s;
  }
}

// ---------------------------------------------------------------------------
// Z-FUSED QKV projection, DOUBLE-BUFFERED async staging (ONE barrier/iter):
// issue global_load_lds for tile k+1 into alt buffer, compute tile k, barrier.
// Block = 128 rows x one head; 48 MFMAs/wave between barriers.
// Epilogue writes MFMA FRAGMENT-ORDER layouts (unchanged from R11).
// ---------------------------------------------------------------------------
__global__ __launch_bounds__(256) void qkv_gemm(
    const ushort_t* __restrict__ Xb,
    const ushort_t* __restrict__ Wqb, const ushort_t* __restrict__ Wkb,
    const ushort_t* __restrict__ Wvb,
    const float* __restrict__ ct, const float* __restrict__ st,
    ushort_t* __restrict__ qfb, ushort_t* __restrict__ kfb, ushort_t* __restrict__ vfb)
{
  // per-buffer: Xs 128x64 (8192) + Ws[3] 64x64 (3*4096) = 20480 ush; x2 = 80 KB
  __shared__ __align__(16) ushort_t smem[2 * 20480];
  const int tid  = threadIdx.x;
  const int wave = tid >> 6;
  const int lane = tid & 63;
  const int l15  = lane & 15, quad = lane >> 4;
  const int h  = blockIdx.x;
  const int n0 = h * 64;
  const int m0 = blockIdx.y * 128;
  const ushort_t* Wsrc[3] = { Wqb, Wkb, Wvb };

  f32x4 acc[3][2][4];
  #pragma unroll
  for (int z = 0; z < 3; ++z)
    #pragma unroll
    for (int i = 0; i < 2; ++i)
      #pragma unroll
      for (int j = 0; j < 4; ++j) acc[z][i][j] = (f32x4){0.f, 0.f, 0.f, 0.f};

  // pre-swizzled gather addresses (global side) + wave-uniform LDS bases
  const int li8 = lane >> 3, lc8 = lane & 7;
  const ushort_t* gX[4]; int lXo[4];
  #pragma unroll
  for (int j = 0; j < 4; ++j) {
    int row = wave * 32 + j * 8 + li8;
    int c = lc8 ^ (row & 7);
    gX[j] = Xb + (size_t)(m0 + row) * E + c * 8;
    lXo[j] = (wave * 32 + j * 8) * 64;
  }
  const ushort_t* gW[3][2]; int lWo[3][2];
  #pragma unroll
  for (int z = 0; z < 3; ++z)
    #pragma unroll
    for (int j = 0; j < 2; ++j) {
      int row = wave * 16 + j * 8 + li8;
      int c = lc8 ^ (row & 7);
      gW[z][j] = Wsrc[z] + (size_t)(n0 + row) * E + c * 8;
      lWo[z][j] = 8192 + z * 4096 + (wave * 16 + j * 8) * 64;
    }

  // stage tile 0 into buffer 0
  #pragma unroll
  for (int j = 0; j < 4; ++j) gl_lds16(gX[j], smem + lXo[j]);
  #pragma unroll
  for (int z = 0; z < 3; ++z)
    #pragma unroll
    for (int j = 0; j < 2; ++j) gl_lds16(gW[z][j], smem + lWo[z][j]);
  __syncthreads();

  for (int k0 = 0; k0 < E; k0 += 64) {
    const int cur = (k0 >> 6) & 1;
    const int nxt = cur ^ 1;
    if (k0 + 64 < E) {
      #pragma unroll
      for (int j = 0; j < 4; ++j) gl_lds16(gX[j] + k0 + 64, smem + nxt * 20480 + lXo[j]);
      #pragma unroll
      for (int z = 0; z < 3; ++z)
        #pragma unroll
        for (int j = 0; j < 2; ++j) gl_lds16(gW[z][j] + k0 + 64, smem + nxt * 20480 + lWo[z][j]);
    }
    const ushort_t* Xs = smem + cur * 20480;
    short8 a[2][2];
    #pragma unroll
    for (int mt = 0; mt < 2; ++mt)
      #pragma unroll
      for (int kh = 0; kh < 2; ++kh)
        a[mt][kh] = *(const short8*)&Xs[swz(wave * 32 + mt * 16 + l15, kh * 32 + quad * 8)];
    #pragma unroll
    for (int z = 0; z < 3; ++z) {
      const ushort_t* Wz = smem + cur * 20480 + 8192 + z * 4096;
      #pragma unroll
      for (int nt = 0; nt < 4; ++nt)
        #pragma unroll
        for (int kh = 0; kh < 2; ++kh) {
          short8 bb = *(const short8*)&Wz[swz(nt * 16 + l15, kh * 32 + quad * 8)];
          #pragma unroll
          for (int mt = 0; mt < 2; ++mt)
            acc[z][mt][nt] = __builtin_amdgcn_mfma_f32_16x16x32_bf16(a[mt][kh], bb, acc[z][mt][nt], 0, 0, 0);
        }
    }
    __syncthreads();
  }

  const int b  = m0 >> 11;
  const int t0 = m0 & (T - 1);
  const int bh = b * H + h;

  // ---- phase Q, then K: rotate -> swz LDS -> fragment-order piece stores ----
  #pragma unroll
  for (int z = 0; z < 2; ++z) {
    const float sc = (z == 0) ? QSCALE : 1.0f;
    #pragma unroll
    for (int mt = 0; mt < 2; ++mt) {
      #pragma unroll
      for (int r = 0; r < 4; ++r) {
        int mloc = wave * 32 + mt * 16 + quad * 4 + r;
        int t = (m0 + mloc) & (T - 1);
        float s0 = acc[z][mt][0][r] * sc;
        float s1 = acc[z][mt][1][r] * sc;
        float c0v = ct[t * 32 + l15],      sn0 = st[t * 32 + l15];
        float c1v = ct[t * 32 + 16 + l15], sn1 = st[t * 32 + 16 + l15];
        smem[swz(mloc, l15)]      = f2bf(s0 * c0v - s1 * sn0);
        smem[swz(mloc, 16 + l15)] = f2bf(s1 * c1v + s0 * sn1);
        smem[swz(mloc, 32 + l15)] = f2bf(acc[z][mt][2][r] * sc);
        smem[swz(mloc, 48 + l15)] = f2bf(acc[z][mt][3][r] * sc);
      }
    }
    __syncthreads();
    if (z == 0) {
      // Qf pieces: p = [qtl:8][kh:2][lane:64]
      #pragma unroll
      for (int i = 0; i < 4; ++i) {
        int p = tid + 256 * i;
        int qtl = p >> 7, kh = (p >> 6) & 1, ln = p & 63;
        int tl = qtl * 16 + (ln & 15);
        int d  = kh * 32 + (ln >> 4) * 8;
        uint4 v = *(const uint4*)&smem[swz(tl, d)];
        size_t off = ((size_t)((bh * 128 + (t0 >> 4) + qtl) * 2 + kh)) * 512 + ln * 8;
        *(uint4*)(qfb + off) = v;
      }
    } else {
      // Kf pieces: p = [ktl:2][mt:4][kh:2][lane:64]
      #pragma unroll
      for (int i = 0; i < 4; ++i) {
        int p = tid + 256 * i;
        int ktl = p >> 9, mt = (p >> 7) & 3, kh = (p >> 6) & 1, ln = p & 63;
        int tl = ktl * 64 + mt * 16 + (ln & 15);
        int d  = kh * 32 + (ln >> 4) * 8;
        uint4 v = *(const uint4*)&smem[swz(tl, d)];
        size_t off = ((size_t)(((bh * 32 + (t0 >> 6) + ktl) * 4 + mt) * 2 + kh)) * 512 + ln * 8;
        *(uint4*)(kfb + off) = v;
      }
    }
    __syncthreads();
  }

  // ---- phase V: rotate -> transposed LDS (d, t_local) stride 132 -> pieces ----
  #pragma unroll
  for (int mt = 0; mt < 2; ++mt) {
    #pragma unroll
    for (int r = 0; r < 4; ++r) {
      int mloc = wave * 32 + mt * 16 + quad * 4 + r;
      int t = (m0 + mloc) & (T - 1);
      float s0 = acc[2][mt][0][r], s1 = acc[2][mt][1][r];
      float c0v = ct[t * 32 + l15],      sn0 = st[t * 32 + l15];
      float c1v = ct[t * 32 + 16 + l15], sn1 = st[t * 32 + 16 + l15];
      smem[(l15)      * 132 + mloc] = f2bf(s0 * c0v - s1 * sn0);
      smem[(16 + l15) * 132 + mloc] = f2bf(s1 * c1v + s0 * sn1);
      smem[(32 + l15) * 132 + mloc] = f2bf(acc[2][mt][2][r]);
      smem[(48 + l15) * 132 + mloc] = f2bf(acc[2][mt][3][r]);
    }
  }
  __syncthreads();
  // Vf pieces: p = [ktl:2][nt:4][kh:2][lane:64]
  #pragma unroll
  for (int i = 0; i < 4; ++i) {
    int p = tid + 256 * i;
    int ktl = p >> 9, nt = (p >> 7) & 3, kh = (p >> 6) & 1, ln = p & 63;
    int d  = nt * 16 + (ln & 15);
    int tl = ktl * 64 + kh * 32 + (ln >> 4) * 8;
    uint4 v = *(const uint4*)&smem[d * 132 + tl];
    size_t off = ((size_t)(((bh * 32 + (t0 >> 6) + ktl) * 4 + nt) * 2 + kh)) * 512 + ln * 8;
    *(uint4*)(vfb + off) = v;
  }
}

// ---------------------------------------------------------------------------
// Flash attention, 2x2 wave split + MFMA ones-trick denominator. Block =
// 64 q x bh; wave (wq,wk) computes its S quadrant; K/V frags direct from
// fragment-order global; no in-loop barriers. Row-sums of P computed by an
// extra MFMA against an all-ones B fragment (moves the softmax-denominator
// adds from VALU to the MFMA pipe; bf16-consistent with the numerator).
// ---------------------------------------------------------------------------
__global__ __launch_bounds__(256) void attn_kernel(
    const ushort_t* __restrict__ qfb, const ushort_t* __restrict__ kfb,
    const ushort_t* __restrict__ vfb, ushort_t* __restrict__ cbuf)
{
  __shared__ __align__(16) ushort_t Ps[4][32 * 40];
  __shared__ __align__(16) float Osh[2][32][66];
  __shared__ float Lsh[2][32];
  const int tid  = threadIdx.x;
  const int wave = tid >> 6;
  const int wq = wave >> 1, wk = wave & 1;
  const int lane = tid & 63;
  const int l15  = lane & 15, quad = lane >> 4;
  const int q0 = blockIdx.x * 64;
  const int bh = blockIdx.y;
  const ushort_t* Qf = qfb + (size_t)bh * (T * HD);
  const ushort_t* Kf = kfb + (size_t)bh * (T * HD);
  const ushort_t* Vf = vfb + (size_t)bh * (T * HD);
  ushort_t* Pw = &Ps[wave][0];

  const short8 ones8 = {(short)0x3F80, (short)0x3F80, (short)0x3F80, (short)0x3F80,
                        (short)0x3F80, (short)0x3F80, (short)0x3F80, (short)0x3F80};

  short8 qa[2][2];
  #pragma unroll
  for (int qg = 0; qg < 2; ++qg)
    #pragma unroll
    for (int kh = 0; kh < 2; ++kh)
      qa[qg][kh] = *(const short8*)(Qf + ((size_t)(((q0 >> 4) + wq * 2 + qg) * 2 + kh)) * 512 + lane * 8);

  short8 ka[2][2], va[4];
  #pragma unroll
  for (int i = 0; i < 2; ++i)
    #pragma unroll
    for (int kh = 0; kh < 2; ++kh)
      ka[i][kh] = *(const short8*)(Kf + ((size_t)((wk * 2 + i) * 2 + kh)) * 512 + lane * 8);
  #pragma unroll
  for (int nt = 0; nt < 4; ++nt)
    va[nt] = *(const short8*)(Vf + ((size_t)(nt * 2 + wk)) * 512 + lane * 8);

  f32x4 o[2][4], osum[2];
  #pragma unroll
  for (int qg = 0; qg < 2; ++qg) {
    #pragma unroll
    for (int nt = 0; nt < 4; ++nt) o[qg][nt] = (f32x4){0.f, 0.f, 0.f, 0.f};
    osum[qg] = (f32x4){0.f, 0.f, 0.f, 0.f};
  }

  for (int kt = 0; kt < T / 64; ++kt) {
    const int ktn = (kt + 1 < T / 64) ? kt + 1 : kt;
    short8 kn[2][2], vn[4];
    #pragma unroll
    for (int i = 0; i < 2; ++i)
      #pragma unroll
      for (int kh = 0; kh < 2; ++kh)
        kn[i][kh] = *(const short8*)(Kf + ((size_t)((ktn * 4 + wk * 2 + i) * 2 + kh)) * 512 + lane * 8);
    #pragma unroll
    for (int nt = 0; nt < 4; ++nt)
      vn[nt] = *(const short8*)(Vf + ((size_t)((ktn * 4 + nt) * 2 + wk)) * 512 + lane * 8);

    f32x4 ss[2][2];
    #pragma unroll
    for (int mt = 0; mt < 2; ++mt)
      #pragma unroll
      for (int qg = 0; qg < 2; ++qg) {
        ss[mt][qg] = (f32x4){0.f, 0.f, 0.f, 0.f};
        ss[mt][qg] = __builtin_amdgcn_mfma_f32_16x16x32_bf16(ka[mt][0], qa[qg][0], ss[mt][qg], 0, 0, 0);
        ss[mt][qg] = __builtin_amdgcn_mfma_f32_16x16x32_bf16(ka[mt][1], qa[qg][1], ss[mt][qg], 0, 0, 0);
      }

    #pragma unroll
    for (int qg = 0; qg < 2; ++qg) {
      #pragma unroll
      for (int mt = 0; mt < 2; ++mt) {
        float p0 = __expf(ss[mt][qg][0]);
        float p1 = __expf(ss[mt][qg][1]);
        float p2 = __expf(ss[mt][qg][2]);
        float p3 = __expf(ss[mt][qg][3]);
        uint2 w2;
        w2.x = pack_bf2(p0, p1);
        w2.y = pack_bf2(p2, p3);
        *(uint2*)&Pw[(qg * 16 + l15) * 40 + mt * 16 + quad * 4] = w2;
      }
    }

    short8 pa0 = *(const short8*)&Pw[(l15) * 40 + quad * 8];
    short8 pa1 = *(const short8*)&Pw[(16 + l15) * 40 + quad * 8];
    osum[0] = __builtin_amdgcn_mfma_f32_16x16x32_bf16(pa0, ones8, osum[0], 0, 0, 0);
    osum[1] = __builtin_amdgcn_mfma_f32_16x16x32_bf16(pa1, ones8, osum[1], 0, 0, 0);
    #pragma unroll
    for (int nt = 0; nt < 4; ++nt) {
      o[0][nt] = __builtin_amdgcn_mfma_f32_16x16x32_bf16(pa0, va[nt], o[0][nt], 0, 0, 0);
      o[1][nt] = __builtin_amdgcn_mfma_f32_16x16x32_bf16(pa1, va[nt], o[1][nt], 0, 0, 0);
    }

    #pragma unroll
    for (int i = 0; i < 2; ++i) {
      ka[i][0] = kn[i][0];
      ka[i][1] = kn[i][1];
    }
    #pragma unroll
    for (int nt = 0; nt < 4; ++nt) va[nt] = vn[nt];
  }

  if (wk == 0) {
    #pragma unroll
    for (int qg = 0; qg < 2; ++qg) {
      #pragma unroll
      for (int nt = 0; nt < 4; ++nt)
        #pragma unroll
        for (int r = 0; r < 4; ++r)
          Osh[wq][qg * 16 + quad * 4 + r][nt * 16 + l15] = o[qg][nt][r];
      if (l15 == 0) {
        #pragma unroll
        for (int r = 0; r < 4; ++r)
          Lsh[wq][qg * 16 + quad * 4 + r] = osum[qg][r];
      }
    }
  }
  __syncthreads();
  if (wk == 1) {
    const int b = bh / H, h = bh % H;
    #pragma unroll
    for (int qg = 0; qg < 2; ++qg) {
      #pragma unroll
      for (int r = 0; r < 4; ++r) {
        float ltot = osum[qg][r] + Lsh[wq][qg * 16 + quad * 4 + r];
        float inv = 1.0f / ltot;
        int t = q0 + wq * 32 + qg * 16 + quad * 4 + r;
        size_t base = ((size_t)b * T + t) * E + h * HD;
        #pragma unroll
        for (int nt = 0; nt < 4; ++nt) {
          float v = o[qg][nt][r] + Osh[wq][qg * 16 + quad * 4 + r][nt * 16 + l15];
          cbuf[base + nt * 16 + l15] = f2bf(v * inv);
        }
      }
    }
  }
}

// ---------------------------------------------------------------------------
// Output projection, 128x64 tile, DOUBLE-BUFFERED async staging (one
// barrier/iter), fp32 out + bias.
// ---------------------------------------------------------------------------
__global__ __launch_bounds__(256) void out_gemm(
    const ushort_t* __restrict__ Xc, const ushort_t* __restrict__ Wob,
    const float* __restrict__ bo, float* __restrict__ out)
{
  // per-buffer: Xs 128x64 (8192) + Ws 64x64 (4096) = 12288 ush; x2 = 48 KB
  __shared__ __align__(16) ushort_t smem[2 * 12288];
  const int tid  = threadIdx.x;
  const int wave = tid >> 6;
  const int lane = tid & 63;
  const int l15  = lane & 15, quad = lane >> 4;
  const int n0 = blockIdx.x * 64;
  const int m0 = blockIdx.y * 128;

  f32x4 acc[2][4];
  #pragma unroll
  for (int i = 0; i < 2; ++i)
    #pragma unroll
    for (int j = 0; j < 4; ++j) acc[i][j] = (f32x4){0.f, 0.f, 0.f, 0.f};

  const int li8 = lane >> 3, lc8 = lane & 7;
  const ushort_t* gX[4]; int lXo[4];
  #pragma unroll
  for (int j = 0; j < 4; ++j) {
    int row = wave * 32 + j * 8 + li8;
    int c = lc8 ^ (row & 7);
    gX[j] = Xc + (size_t)(m0 + row) * E + c * 8;
    lXo[j] = (wave * 32 + j * 8) * 64;
  }
  const ushort_t* gW[2]; int lWo[2];
  #pragma unroll
  for (int j = 0; j < 2; ++j) {
    int row = wave * 16 + j * 8 + li8;
    int c = lc8 ^ (row & 7);
    gW[j] = Wob + (size_t)(n0 + row) * E + c * 8;
    lWo[j] = 8192 + (wave * 16 + j * 8) * 64;
  }

  #pragma unroll
  for (int j = 0; j < 4; ++j) gl_lds16(gX[j], smem + lXo[j]);
  #pragma unroll
  for (int j = 0; j < 2; ++j) gl_lds16(gW[j], smem + lWo[j]);
  __syncthreads();

  for (int k0 = 0; k0 < E; k0 += 64) {
    const int cur = (k0 >> 6) & 1;
    const int nxt = cur ^ 1;
    if (k0 + 64 < E) {
      #pragma unroll
      for (int j = 0; j < 4; ++j) gl_lds16(gX[j] + k0 + 64, smem + nxt * 12288 + lXo[j]);
      #pragma unroll
      for (int j = 0; j < 2; ++j) gl_lds16(gW[j] + k0 + 64, smem + nxt * 12288 + lWo[j]);
    }
    const ushort_t* Xs = smem + cur * 12288;
    const ushort_t* Ws = smem + cur * 12288 + 8192;
    short8 a[2][2];
    #pragma unroll
    for (int mt = 0; mt < 2; ++mt)
      #pragma unroll
      for (int kh = 0; kh < 2; ++kh)
        a[mt][kh] = *(const short8*)&Xs[swz(wave * 32 + mt * 16 + l15, kh * 32 + quad * 8)];
    #pragma unroll
    for (int nt = 0; nt < 4; ++nt) {
      #pragma unroll
      for (int kh = 0; kh < 2; ++kh) {
        short8 bb = *(const short8*)&Ws[swz(nt * 16 + l15, kh * 32 + quad * 8)];
        #pragma unroll
        for (int mt = 0; mt < 2; ++mt)
          acc[mt][nt] = __builtin_amdgcn_mfma_f32_16x16x32_bf16(a[mt][kh], bb, acc[mt][nt], 0, 0, 0);
      }
    }
    __syncthreads();
  }

  float bias[4];
  #pragma unroll
  for (int nt = 0; nt < 4; ++nt) bias[nt] = bo[n0 + nt * 16 + l15];
  #pragma unroll
  for (int mt = 0; mt < 2; ++mt) {
    #pragma unroll
    for (int r = 0; r < 4; ++r) {
      int m = m0 + wave * 32 + mt * 16 + quad * 4 + r;
      float* op = out + (size_t)m * E + n0;
      op[l15]      = acc[mt][0][r] + bias[0];
      op[16 + l15] = acc[mt][1][r] + bias[1];
      op[32 + l15] = acc[mt][2][r] + bias[2];
      op[48 + l15] = acc[mt][3][r] + bias[3];
    }
  }
}

// ---------------------------------------------------------------------------
extern "C" void kernel_launch(void* const* d_in, const int* in_sizes, int n_in,
                              void* d_out, int out_size, void* d_ws, size_t ws_size,
                              hipStream_t stream) {
  (void)in_sizes; (void)n_in; (void)out_size; (void)ws_size;
  const float* X    = (const float*)d_in[0];
  const float* rope = (const float*)d_in[1];
  const float* Wq   = (const float*)d_in[2];
  const float* Wk   = (const float*)d_in[3];
  const float* Wv   = (const float*)d_in[4];
  const float* Wo   = (const float*)d_in[5];
  const float* bo   = (const float*)d_in[6];
  float* out = (float*)d_out;

  const size_t NX = (size_t)B * T * E;
  const size_t NW = (size_t)E * E;
  const size_t NR = (size_t)T * 32;
  ushort_t* Xb  = (ushort_t*)d_ws;
  ushort_t* Wqb = Xb  + NX;
  ushort_t* Wkb = Wqb + NW;
  ushort_t* Wvb = Wkb + NW;
  ushort_t* Wob = Wvb + NW;
  ushort_t* qfb = Wob + NW;
  ushort_t* kfb = qfb + NX;
  ushort_t* vfb = kfb + NX;
  ushort_t* cb  = vfb + NX;
  float* ct = (float*)(cb + NX);
  float* st = ct + NR;

  const int total4 = (int)((NX + 4 * NW + NR) / 4);
  cvt_all<<<total4 / 256, 256, 0, stream>>>(X, Wq, Wk, Wv, Wo, rope,
                                            Xb, Wqb, Wkb, Wvb, Wob, ct, st);

  qkv_gemm<<<dim3(H, (B * T) / 128), 256, 0, stream>>>(
      Xb, Wqb, Wkb, Wvb, ct, st, qfb, kfb, vfb);
  attn_kernel<<<dim3(T / 64, B * H), 256, 0, stream>>>(qfb, kfb, vfb, cb);
  out_gemm<<<dim3(E / 64, (B * T) / 128), 256, 0, stream>>>(cb, Wob, bo, out);
}